// Round 2
// baseline (153.830 us; speedup 1.0000x reference)
//
#include <hip/hip_runtime.h>
#include <stdint.h>

typedef __bf16 bf16;
typedef bf16 bf16x8 __attribute__((ext_vector_type(8)));
typedef float floatx4 __attribute__((ext_vector_type(4)));

#define INV_T     2.0f                      // 1 / TEMPERATURE
#define SQRT_K    1.6986436206f             // sqrt(INV_T * log2(e))
#define INV_K     0.34657359028f            // ln(2)/2 = 1/(INV_T*log2(e))
#define GLOBAL_AS __attribute__((address_space(1)))
#define LDS_AS    __attribute__((address_space(3)))

// rep2 layout (16B chunks): chunk(r, ch) = (r>>6)*1024 + ch*64 + (r&63),
// ch = k>>3. MFMA A/B fragment loads and tile staging are fully coalesced,
// LDS fragment reads structurally conflict-free.

// ---------------------------------------------------------------------------
// Kernel 1: L2-normalize rows, scale by SQRT_K, write bf16 rep2 (swizzled).
// Also zeroes out + the 32 per-group completion counters (ws is re-poisoned
// every iteration, so they MUST be re-zeroed in-stream before sim).
// ---------------------------------------------------------------------------
__global__ __launch_bounds__(256) void nrm_kernel(const float* __restrict__ p1,
                                                  const float* __restrict__ p2,
                                                  uint32_t* __restrict__ rep2,
                                                  float* __restrict__ out,
                                                  uint32_t* __restrict__ cnt) {
    int gt   = blockIdx.x * 256 + threadIdx.x;
    int row  = gt >> 6;
    int lane = gt & 63;
    const float* srcRow = (row < 4096) ? (p1 + (size_t)row * 128)
                                       : (p2 + (size_t)(row - 4096) * 128);
    float2 v = ((const float2*)srcRow)[lane];
    float ss = v.x * v.x + v.y * v.y;
#pragma unroll
    for (int s = 1; s < 64; s <<= 1) ss += __shfl_xor(ss, s, 64);
    float inv = SQRT_K / fmaxf(sqrtf(ss), 1e-12f);
    union { bf16 h[2]; uint32_t u; } pk;
    pk.h[0] = (bf16)(v.x * inv);
    pk.h[1] = (bf16)(v.y * inv);
    int chunk = (row >> 6) * 1024 + (lane >> 2) * 64 + (row & 63);
    rep2[chunk * 4 + (lane & 3)] = pk.u;
    if (gt < 32) cnt[gt] = 0;
    if (gt == 0) *out = 0.0f;
}

// ---------------------------------------------------------------------------
// Kernel 2: SYMMETRIC rowsum partials + positive-pair dot + FUSED finish.
// Exact 528-block 1-D grid, decoded to upper-triangle (rb, cb), cb >= rb.
// Each block:
//   row partials (sum over its 256 cols)  -> rowsumP[row][cb]
//   col partials (sum over its 256 rows)  -> rowsumP[col][rb]   (cb != rb)
// Partner tiles (rb, rb+16) write pos[i] / pos[i+4096] from strip diagonal.
//
// FUSED FINISH (R11): after stores, release-fence + atomicAdd cnt[rb],
// cnt[cb]. Group g receives exactly 32 increments (32-g row writers incl.
// diag + g col writers). The 32nd incrementer acquire-fences and computes
// sum_i [log(sum_c rowsumP[i][c]) - 2*pos_i] for its 256 rows, atomicAdd
// into out. Replaces the fin kernel (launch + dispatch saved); 31/32 group
// finishes overlap with still-running blocks.
//
// REGISTER-BUDGET HISTORY (don't re-tighten):
//   (256,4): 128-reg cap -> aF spills, 66 MB scratch, 85 us  (R7)
//   (256,3): 170-reg cap -> still spills (VGPR=84, 36 MB, 43 us)  (R8)
//   (256,2): 256-reg cap -> live set (~130) fits, no spill.
// ---------------------------------------------------------------------------
__global__ __launch_bounds__(256, 2) void sim_kernel(const uint4* __restrict__ rep2,
                                                     float* __restrict__ rowsumP,
                                                     float* __restrict__ pos,
                                                     uint32_t* __restrict__ cnt,
                                                     float* __restrict__ out) {
    __shared__ uint4 lB[4096];          // 64 KB: full 256-col x 128-k B panel
    __shared__ float colPart[4][256];   // 4 KB cross-wave colsum combine
    __shared__ unsigned lastFlags;

    // triangular decode: j -> (rb, cb), rb-major, cb ascending, cb >= rb
    const int j  = blockIdx.x;          // 0..527
    int jpp = 527 - j;                  // index from the end
    int m = (int)((sqrtf((float)(8 * jpp + 1)) - 1.0f) * 0.5f);
    while ((m + 1) * (m + 2) / 2 <= jpp) ++m;   // integer fixup (exact)
    while (m * (m + 1) / 2 > jpp) --m;
    const int rb = 31 - m;
    const int cb = 31 - (jpp - m * (m + 1) / 2);

    const int tid  = threadIdx.x;
    const int w    = tid >> 6;
    const int lane = tid & 63;
    const int quad = lane >> 4;
    const int lcol = lane & 15;

    // Stage the WHOLE B panel in one shot: rep2[cb*4096 .. +4096) uint4s.
    // LDS dest linear in tid (wave-uniform base + lane*16): legal for
    // global_load_lds. Drained by the single barrier below.
    {
        const uint4* src = rep2 + (size_t)cb * 4096;
#pragma unroll
        for (int jj = 0; jj < 16; jj++)
            __builtin_amdgcn_global_load_lds(
                (const GLOBAL_AS uint32_t*)(src + jj * 256 + tid),
                (LDS_AS uint32_t*)&lB[jj * 256 + tid], 16, 0, 0);
    }

    const int wbase = rb * 256 + w * 64;       // wave's rows (64-aligned)
    const int pbase = (wbase + 4096) & 8191;   // partner 64-col window

    // A fragments: rows wbase+mi*16+lcol, k = ks*32+quad*8..+7
    bf16x8 aF[4][4];
    const uint4* aG = rep2 + (size_t)(wbase >> 6) * 1024;
#pragma unroll
    for (int mi = 0; mi < 4; mi++)
#pragma unroll
        for (int ks = 0; ks < 4; ks++)
            aF[mi][ks] = *(const bf16x8*)&aG[(ks * 4 + quad) * 64 + mi * 16 + lcol];

    float rs[16];
#pragma unroll
    for (int i = 0; i < 16; i++) rs[i] = 0.0f;

    __syncthreads();   // one drain: panel in LDS, aF in regs

    // 16 subtiles, no barriers anywhere inside.
#pragma unroll
    for (int t = 0; t < 4; t++) {
#pragma unroll
        for (int so = 0; so < 4; so++) {
            bf16x8 bF[4];
#pragma unroll
            for (int ks = 0; ks < 4; ks++)
                bF[ks] = *(const bf16x8*)&lB[t * 1024 + (ks * 4 + quad) * 64 + so * 16 + lcol];

            floatx4 acc[4];
            const floatx4 zf = {0.0f, 0.0f, 0.0f, 0.0f};
#pragma unroll
            for (int mi = 0; mi < 4; mi++) acc[mi] = zf;
#pragma unroll
            for (int ks = 0; ks < 4; ks++)
#pragma unroll
                for (int mi = 0; mi < 4; mi++)
                    acc[mi] = __builtin_amdgcn_mfma_f32_16x16x32_bf16(
                        aF[mi][ks], bF[ks], acc[mi], 0, 0, 0);

            const int c0s  = cb * 256 + t * 64 + so * 16;
            const int gcol = c0s + lcol;
            const bool diagS = ((c0s & ~63) == wbase);   // => rb==cb && t==w
            const bool partS = ((c0s & ~63) == pbase);   // => cb==rb+16 && t==w
            float cs = 0.0f;                             // colsum partial
            if (diagS | partS) {
#pragma unroll
                for (int mi = 0; mi < 4; mi++)
#pragma unroll
                    for (int r = 0; r < 4; r++) {
                        int grow = wbase + mi * 16 + quad * 4 + r;
                        float s = acc[mi][r];
                        if (partS && gcol == grow + 4096) {   // rb<16 here
                            float d = s * INV_K;              // raw dot
                            pos[grow] = d;
                            pos[grow + 4096] = d;
                        }
                        float e = __builtin_amdgcn_exp2f(s);
                        if (diagS && grow == gcol) e = 0.0f;  // mask j == i
                        rs[mi * 4 + r] += e;
                        cs += e;
                    }
            } else {
#pragma unroll
                for (int mi = 0; mi < 4; mi++)
#pragma unroll
                    for (int r = 0; r < 4; r++) {
                        float e = __builtin_amdgcn_exp2f(acc[mi][r]);
                        rs[mi * 4 + r] += e;
                        cs += e;
                    }
            }
            // colsum over the wave's 64 rows: reduce across quads
            cs += __shfl_xor(cs, 16, 64);
            cs += __shfl_xor(cs, 32, 64);
            if (quad == 0) colPart[w][t * 64 + so * 16 + lcol] = cs;
        }
    }

    // row partials: reduce rs across lane bits 0-3 (16 cols per quad)
#pragma unroll
    for (int s = 1; s < 16; s <<= 1)
#pragma unroll
        for (int k = 0; k < 16; k++) rs[k] += __shfl_xor(rs[k], s, 64);

    if (lcol == 0) {
#pragma unroll
        for (int k = 0; k < 16; k++) {
            int grow = wbase + (k >> 2) * 16 + quad * 4 + (k & 3);
            rowsumP[(size_t)grow * 32 + cb] = rs[k];   // slot cb
        }
    }

    __syncthreads();   // colPart visibility for the cross-wave combine

    // col partials -> mirror rows' slot rb (skip self-tile)
    if (rb != cb) {
        float c = colPart[0][tid] + colPart[1][tid] + colPart[2][tid] + colPart[3][tid];
        rowsumP[(size_t)(cb * 256 + tid) * 32 + rb] = c;
    }

    // ---- fused finish: completion counters + distributed fin ----
    __threadfence();   // release: rowsumP/pos stores visible device-wide
    __syncthreads();   // all threads' fences done before tid0's atomics
    if (tid == 0) {
        unsigned f = 0;
        if (atomicAdd(&cnt[rb], 1u) == 31u) f |= 1u;
        if (rb != cb && atomicAdd(&cnt[cb], 1u) == 31u) f |= 2u;
        lastFlags = f;
    }
    __syncthreads();
    unsigned f = lastFlags;
    if (f) {
        __threadfence();   // acquire: see all 32 writers' slots
        float v = 0.0f;
#pragma unroll
        for (int gsel = 0; gsel < 2; gsel++) {
            if (!(f & (1u << gsel))) continue;
            int g   = gsel ? cb : rb;
            int row = g * 256 + tid;
            const floatx4* rp = (const floatx4*)(rowsumP + (size_t)row * 32);
            float d = 0.0f;
#pragma unroll
            for (int q = 0; q < 8; q++) {
                floatx4 qv = rp[q];
                d += (qv[0] + qv[1]) + (qv[2] + qv[3]);
            }
            v += logf(d) - pos[row] * INV_T;
        }
#pragma unroll
        for (int s = 1; s < 64; s <<= 1) v += __shfl_xor(v, s, 64);
        if (lane == 0) colPart[0][w] = v;   // reuse LDS (sync'd below)
        __syncthreads();
        if (tid == 0)
            atomicAdd(out, (colPart[0][0] + colPart[0][1] + colPart[0][2] + colPart[0][3])
                               * (1.0f / 8192.0f));
    }
}

extern "C" void kernel_launch(void* const* d_in, const int* in_sizes, int n_in,
                              void* d_out, int out_size, void* d_ws, size_t ws_size,
                              hipStream_t stream) {
    const float* p1 = (const float*)d_in[0];
    const float* p2 = (const float*)d_in[1];
    float* out = (float*)d_out;

    char* ws       = (char*)d_ws;
    uint32_t* rep2 = (uint32_t*)ws;                             // 2 MB
    float* rowsumP = (float*)(ws + (2u << 20));                 // 1 MB
    float* pos     = (float*)(ws + (3u << 20));                 // 32 KB
    uint32_t* cnt  = (uint32_t*)(ws + (3u << 20) + (32u << 10)); // 128 B

    nrm_kernel<<<2048, 256, 0, stream>>>(p1, p2, rep2, out, cnt);
    sim_kernel<<<528, 256, 0, stream>>>((const uint4*)rep2, rowsumP, pos, cnt, out);
}

// Round 4
// 107.529 us; speedup vs baseline: 1.4306x; 1.4306x over previous
//
#include <hip/hip_runtime.h>
#include <stdint.h>

typedef __bf16 bf16;
typedef bf16 bf16x8 __attribute__((ext_vector_type(8)));
typedef float floatx4 __attribute__((ext_vector_type(4)));

#define INV_T     2.0f                      // 1 / TEMPERATURE
#define SQRT_K    1.6986436206f             // sqrt(INV_T * log2(e))
#define INV_K     0.34657359028f            // ln(2)/2 = 1/(INV_T*log2(e))
#define GLOBAL_AS __attribute__((address_space(1)))
#define LDS_AS    __attribute__((address_space(3)))

// rep2 layout (16B chunks): chunk(r, ch) = (r>>6)*1024 + ch*64 + (r&63),
// ch = k>>3. MFMA A/B fragment loads and tile staging are fully coalesced,
// LDS fragment reads structurally conflict-free.

// ---------------------------------------------------------------------------
// Kernel 1: L2-normalize rows, scale by SQRT_K, write bf16 rep2 (swizzled).
// Also zeroes out + the 32 per-group completion counters (ws is re-poisoned
// every iteration, so they MUST be re-zeroed in-stream before sim).
// ---------------------------------------------------------------------------
__global__ __launch_bounds__(256) void nrm_kernel(const float* __restrict__ p1,
                                                  const float* __restrict__ p2,
                                                  uint32_t* __restrict__ rep2,
                                                  float* __restrict__ out,
                                                  uint32_t* __restrict__ cnt) {
    int gt   = blockIdx.x * 256 + threadIdx.x;
    int row  = gt >> 6;
    int lane = gt & 63;
    const float* srcRow = (row < 4096) ? (p1 + (size_t)row * 128)
                                       : (p2 + (size_t)(row - 4096) * 128);
    float2 v = ((const float2*)srcRow)[lane];
    float ss = v.x * v.x + v.y * v.y;
#pragma unroll
    for (int s = 1; s < 64; s <<= 1) ss += __shfl_xor(ss, s, 64);
    float inv = SQRT_K / fmaxf(sqrtf(ss), 1e-12f);
    union { bf16 h[2]; uint32_t u; } pk;
    pk.h[0] = (bf16)(v.x * inv);
    pk.h[1] = (bf16)(v.y * inv);
    int chunk = (row >> 6) * 1024 + (lane >> 2) * 64 + (row & 63);
    rep2[chunk * 4 + (lane & 3)] = pk.u;
    if (gt < 32) cnt[gt] = 0;
    if (gt == 0) *out = 0.0f;
}

// ---------------------------------------------------------------------------
// Kernel 2: SYMMETRIC rowsum partials + positive-pair dot + FUSED finish.
// dim3(32,32) grid, upper-triangle blocks only (cb >= rb; lower exits).
// Each block:
//   row partials (sum over its 256 cols)  -> rowsumP[row][cb]
//   col partials (sum over its 256 rows)  -> rowsumP[col][rb]   (cb != rb)
// Partner tiles (rb, rb+16) write pos[i] / pos[i+4096] from strip diagonal.
//
// FUSED FINISH (R12, fence-free): R11's __threadfence() lowered to
// buffer_wbl2/buffer_inv sc1 (cache-WIDE L2 writeback/invalidate) per block
// -> ~100us of serialized TCC maintenance (MfmaUtil 3%, all idle). Fix:
// per-ACCESS coherence instead of cache-wide fences. Cross-block data
// (rowsumP, pos) is written with atomicExch (RMW executes at the MALL
// coherence point, never dirty in a local L2) and read with
// __hip_atomic_load(AGENT) (global_load sc1, bypasses non-coherent L2).
// Ordering: per-thread s_waitcnt vmcnt(0) (exchanges MALL-acked) ->
// __syncthreads -> tid0 bumps cnt[rb]/cnt[cb] (relaxed atomicAdd). MALL
// serializes per address, so cnt==31 implies all 32 writers' data applied.
// The 32nd incrementer computes that group's sum_i[log(rowsum_i)-2*pos_i]
// and atomicAdds into out. NO wbl2/inv anywhere.
//
// REGISTER-BUDGET HISTORY (don't re-tighten):
//   (256,4): 128-reg cap -> aF spills, 66 MB scratch, 85 us  (R7)
//   (256,3): 170-reg cap -> still spills (VGPR=84, 36 MB, 43 us)  (R8)
//   (256,2): 256-reg cap -> live set (~130) fits, no spill.
// ---------------------------------------------------------------------------
__global__ __launch_bounds__(256, 2) void sim_kernel(const uint4* __restrict__ rep2,
                                                     float* __restrict__ rowsumP,
                                                     float* __restrict__ pos,
                                                     uint32_t* __restrict__ cnt,
                                                     float* __restrict__ out) {
    __shared__ uint4 lB[4096];          // 64 KB: full 256-col x 128-k B panel
    __shared__ float colPart[4][256];   // 4 KB cross-wave colsum combine
    __shared__ unsigned lastFlags;

    const int cb = blockIdx.x;     // col block: cols [cb*256, +256)
    const int rb = blockIdx.y;     // row block: rows [rb*256, +256)
    if (cb < rb) return;           // symmetry: upper triangle only

    const int tid  = threadIdx.x;
    const int w    = tid >> 6;
    const int lane = tid & 63;
    const int quad = lane >> 4;
    const int lcol = lane & 15;

    // Stage the WHOLE B panel in one shot: rep2[cb*4096 .. +4096) uint4s.
    // LDS dest linear in tid (wave-uniform base + lane*16): legal for
    // global_load_lds. Drained by the single barrier below.
    {
        const uint4* src = rep2 + (size_t)cb * 4096;
#pragma unroll
        for (int jj = 0; jj < 16; jj++)
            __builtin_amdgcn_global_load_lds(
                (const GLOBAL_AS uint32_t*)(src + jj * 256 + tid),
                (LDS_AS uint32_t*)&lB[jj * 256 + tid], 16, 0, 0);
    }

    const int wbase = rb * 256 + w * 64;       // wave's rows (64-aligned)
    const int pbase = (wbase + 4096) & 8191;   // partner 64-col window

    // A fragments: rows wbase+mi*16+lcol, k = ks*32+quad*8..+7
    bf16x8 aF[4][4];
    const uint4* aG = rep2 + (size_t)(wbase >> 6) * 1024;
#pragma unroll
    for (int mi = 0; mi < 4; mi++)
#pragma unroll
        for (int ks = 0; ks < 4; ks++)
            aF[mi][ks] = *(const bf16x8*)&aG[(ks * 4 + quad) * 64 + mi * 16 + lcol];

    float rs[16];
#pragma unroll
    for (int i = 0; i < 16; i++) rs[i] = 0.0f;

    __syncthreads();   // one drain: panel in LDS, aF in regs

    // 16 subtiles, no barriers anywhere inside.
#pragma unroll
    for (int t = 0; t < 4; t++) {
#pragma unroll
        for (int so = 0; so < 4; so++) {
            bf16x8 bF[4];
#pragma unroll
            for (int ks = 0; ks < 4; ks++)
                bF[ks] = *(const bf16x8*)&lB[t * 1024 + (ks * 4 + quad) * 64 + so * 16 + lcol];

            floatx4 acc[4];
            const floatx4 zf = {0.0f, 0.0f, 0.0f, 0.0f};
#pragma unroll
            for (int mi = 0; mi < 4; mi++) acc[mi] = zf;
#pragma unroll
            for (int ks = 0; ks < 4; ks++)
#pragma unroll
                for (int mi = 0; mi < 4; mi++)
                    acc[mi] = __builtin_amdgcn_mfma_f32_16x16x32_bf16(
                        aF[mi][ks], bF[ks], acc[mi], 0, 0, 0);

            const int c0s  = cb * 256 + t * 64 + so * 16;
            const int gcol = c0s + lcol;
            const bool diagS = ((c0s & ~63) == wbase);   // => rb==cb && t==w
            const bool partS = ((c0s & ~63) == pbase);   // => cb==rb+16 && t==w
            float cs = 0.0f;                             // colsum partial
            if (diagS | partS) {
#pragma unroll
                for (int mi = 0; mi < 4; mi++)
#pragma unroll
                    for (int r = 0; r < 4; r++) {
                        int grow = wbase + mi * 16 + quad * 4 + r;
                        float s = acc[mi][r];
                        if (partS && gcol == grow + 4096) {   // rb<16 here
                            float d = s * INV_K;              // raw dot
                            atomicExch(&pos[grow], d);        // MALL-coherent
                            atomicExch(&pos[grow + 4096], d);
                        }
                        float e = __builtin_amdgcn_exp2f(s);
                        if (diagS && grow == gcol) e = 0.0f;  // mask j == i
                        rs[mi * 4 + r] += e;
                        cs += e;
                    }
            } else {
#pragma unroll
                for (int mi = 0; mi < 4; mi++)
#pragma unroll
                    for (int r = 0; r < 4; r++) {
                        float e = __builtin_amdgcn_exp2f(acc[mi][r]);
                        rs[mi * 4 + r] += e;
                        cs += e;
                    }
            }
            // colsum over the wave's 64 rows: reduce across quads
            cs += __shfl_xor(cs, 16, 64);
            cs += __shfl_xor(cs, 32, 64);
            if (quad == 0) colPart[w][t * 64 + so * 16 + lcol] = cs;
        }
    }

    // row partials: reduce rs across lane bits 0-3 (16 cols per quad)
#pragma unroll
    for (int s = 1; s < 16; s <<= 1)
#pragma unroll
        for (int k = 0; k < 16; k++) rs[k] += __shfl_xor(rs[k], s, 64);

    if (lcol == 0) {
#pragma unroll
        for (int k = 0; k < 16; k++) {
            int grow = wbase + (k >> 2) * 16 + quad * 4 + (k & 3);
            atomicExch(&rowsumP[(size_t)grow * 32 + cb], rs[k]);   // slot cb
        }
    }

    __syncthreads();   // colPart visibility for the cross-wave combine

    // col partials -> mirror rows' slot rb (skip self-tile)
    if (rb != cb) {
        float c = colPart[0][tid] + colPart[1][tid] + colPart[2][tid] + colPart[3][tid];
        atomicExch(&rowsumP[(size_t)(cb * 256 + tid) * 32 + rb], c);
    }

    // ---- fused finish: fence-free completion counters ----
    // Per-thread: all my exchanges MALL-acked. Then barrier joins all 256.
    asm volatile("s_waitcnt vmcnt(0)" ::: "memory");
    __syncthreads();
    if (tid == 0) {
        unsigned f = 0;
        if (__hip_atomic_fetch_add(&cnt[rb], 1u, __ATOMIC_RELAXED,
                                   __HIP_MEMORY_SCOPE_AGENT) == 31u) f |= 1u;
        if (rb != cb &&
            __hip_atomic_fetch_add(&cnt[cb], 1u, __ATOMIC_RELAXED,
                                   __HIP_MEMORY_SCOPE_AGENT) == 31u) f |= 2u;
        lastFlags = f;
    }
    __syncthreads();
    unsigned f = lastFlags;
    if (f) {
        asm volatile("" ::: "memory");   // keep loads below the flag check
        float v = 0.0f;
#pragma unroll
        for (int gsel = 0; gsel < 2; gsel++) {
            if (!(f & (1u << gsel))) continue;
            int g   = gsel ? cb : rb;
            int row = g * 256 + tid;
            const float* rp = rowsumP + (size_t)row * 32;
            float d = 0.0f;
#pragma unroll
            for (int q = 0; q < 32; q++)
                d += __hip_atomic_load(rp + q, __ATOMIC_RELAXED,
                                       __HIP_MEMORY_SCOPE_AGENT);
            float p = __hip_atomic_load(pos + row, __ATOMIC_RELAXED,
                                        __HIP_MEMORY_SCOPE_AGENT);
            v += logf(d) - p * INV_T;
        }
#pragma unroll
        for (int s = 1; s < 64; s <<= 1) v += __shfl_xor(v, s, 64);
        if (lane == 0) colPart[0][w] = v;   // reuse LDS (sync'd below)
        __syncthreads();
        if (tid == 0)
            atomicAdd(out, (colPart[0][0] + colPart[0][1] + colPart[0][2] + colPart[0][3])
                               * (1.0f / 8192.0f));
    }
}

extern "C" void kernel_launch(void* const* d_in, const int* in_sizes, int n_in,
                              void* d_out, int out_size, void* d_ws, size_t ws_size,
                              hipStream_t stream) {
    const float* p1 = (const float*)d_in[0];
    const float* p2 = (const float*)d_in[1];
    float* out = (float*)d_out;

    char* ws       = (char*)d_ws;
    uint32_t* rep2 = (uint32_t*)ws;                             // 2 MB
    float* rowsumP = (float*)(ws + (2u << 20));                 // 1 MB
    float* pos     = (float*)(ws + (3u << 20));                 // 32 KB
    uint32_t* cnt  = (uint32_t*)(ws + (3u << 20) + (32u << 10)); // 128 B

    nrm_kernel<<<2048, 256, 0, stream>>>(p1, p2, rep2, out, cnt);
    sim_kernel<<<dim3(32, 32), 256, 0, stream>>>((const uint4*)rep2, rowsumP, pos, cnt, out);
}

// Round 5
// 91.306 us; speedup vs baseline: 1.6848x; 1.1777x over previous
//
#include <hip/hip_runtime.h>
#include <stdint.h>

typedef __bf16 bf16;
typedef bf16 bf16x8 __attribute__((ext_vector_type(8)));
typedef float floatx4 __attribute__((ext_vector_type(4)));

#define INV_T     2.0f                      // 1 / TEMPERATURE
#define SQRT_K    1.6986436206f             // sqrt(INV_T * log2(e))
#define INV_K     0.34657359028f            // ln(2)/2 = 1/(INV_T*log2(e))

// rep2 layout (16B chunks): chunk(r, ch) = (r>>6)*1024 + ch*64 + (r&63),
// ch = k>>3. MFMA A/B fragment loads are fully coalesced (4x256B segments
// per 16B-per-lane load).

// ---------------------------------------------------------------------------
// Kernel 1: L2-normalize rows, scale by SQRT_K, write bf16 rep2 (swizzled).
// ---------------------------------------------------------------------------
__global__ __launch_bounds__(256) void nrm_kernel(const float* __restrict__ p1,
                                                  const float* __restrict__ p2,
                                                  uint32_t* __restrict__ rep2,
                                                  float* __restrict__ out) {
    int gt   = blockIdx.x * 256 + threadIdx.x;
    int row  = gt >> 6;
    int lane = gt & 63;
    const float* srcRow = (row < 4096) ? (p1 + (size_t)row * 128)
                                       : (p2 + (size_t)(row - 4096) * 128);
    float2 v = ((const float2*)srcRow)[lane];
    float ss = v.x * v.x + v.y * v.y;
#pragma unroll
    for (int s = 1; s < 64; s <<= 1) ss += __shfl_xor(ss, s, 64);
    float inv = SQRT_K / fmaxf(sqrtf(ss), 1e-12f);
    union { bf16 h[2]; uint32_t u; } pk;
    pk.h[0] = (bf16)(v.x * inv);
    pk.h[1] = (bf16)(v.y * inv);
    int chunk = (row >> 6) * 1024 + (lane >> 2) * 64 + (row & 63);
    rep2[chunk * 4 + (lane & 3)] = pk.u;
    if (gt == 0) *out = 0.0f;
}

// ---------------------------------------------------------------------------
// Kernel 2: SYMMETRIC rowsum partials + positive-pair dot.
// dim3(32,32) grid, upper-triangle blocks only (cb >= rb; lower exits).
//   row partials (sum over its 256 cols)  -> rowsumP[row][cb]
//   col partials (sum over its 256 rows)  -> rowsumP[col][rb]   (cb != rb)
// Partner tiles (rb, rb+16) write pos[i] / pos[i+4096] from strip diagonal.
//
// R13 STRUCTURE CHANGE (occupancy/latency theory): R10's sim measured ~33us
// vs ~6us work model: MfmaUtil 5%, Occupancy 6.5% -> 75% idle. Cause: 68KB
// LDS B-panel -> 2 blocks/CU (2 waves/SIMD) + stage->full-drain-barrier->
// compute serialization, with nothing to hide latency. But rep2 is 2MB --
// L2-RESIDENT per XCD (4MB). Per guide Common-mistake #7 (staging L2-fit
// data is pure overhead, measured +26% when dropped): B fragments now read
// DIRECT from global/L2 with the same swizzled, coalesced pattern as the A
// fragments. No staging, no stage barrier, LDS 68KB -> 4KB; occupancy is
// VGPR-bound (~4 waves/SIMD). Extra L2 traffic (each wave reads the panel
// privately, ~170MB aggregate @34.5TB/s ~ 5us chip-wide) is cheap vs the
// ~25us of stall removed.
//
// REGISTER-BUDGET HISTORY (don't re-tighten):
//   (256,4): 128-reg cap -> aF spills, 66 MB scratch, 85 us  (R7)
//   (256,3): 170-reg cap -> still spills (VGPR=84, 36 MB, 43 us)  (R8)
//   (256,2): 256-reg cap -> live set fits, no spill.
// ---------------------------------------------------------------------------
__global__ __launch_bounds__(256, 2) void sim_kernel(const uint4* __restrict__ rep2,
                                                     float* __restrict__ rowsumP,
                                                     float* __restrict__ pos) {
    __shared__ float colPart[4][256];   // 4 KB cross-wave colsum combine

    const int cb = blockIdx.x;     // col block: cols [cb*256, +256)
    const int rb = blockIdx.y;     // row block: rows [rb*256, +256)
    if (cb < rb) return;           // symmetry: upper triangle only

    const int tid  = threadIdx.x;
    const int w    = tid >> 6;
    const int lane = tid & 63;
    const int quad = lane >> 4;
    const int lcol = lane & 15;

    const int wbase = rb * 256 + w * 64;       // wave's rows (64-aligned)
    const int pbase = (wbase + 4096) & 8191;   // partner 64-col window

    // A fragments: rows wbase+mi*16+lcol, k = ks*32+quad*8..+7 (direct, L2)
    bf16x8 aF[4][4];
    const uint4* aG = rep2 + (size_t)(wbase >> 6) * 1024;
#pragma unroll
    for (int mi = 0; mi < 4; mi++)
#pragma unroll
        for (int ks = 0; ks < 4; ks++)
            aF[mi][ks] = *(const bf16x8*)&aG[(ks * 4 + quad) * 64 + mi * 16 + lcol];

    // B panel base for this col block (direct from L2, same layout as A)
    const uint4* bG = rep2 + (size_t)cb * 4096;

    float rs[16];
#pragma unroll
    for (int i = 0; i < 16; i++) rs[i] = 0.0f;

    // 16 subtiles, no barriers anywhere inside.
#pragma unroll
    for (int t = 0; t < 4; t++) {
#pragma unroll
        for (int so = 0; so < 4; so++) {
            bf16x8 bF[4];
#pragma unroll
            for (int ks = 0; ks < 4; ks++)
                bF[ks] = *(const bf16x8*)&bG[t * 1024 + (ks * 4 + quad) * 64 + so * 16 + lcol];

            floatx4 acc[4];
            const floatx4 zf = {0.0f, 0.0f, 0.0f, 0.0f};
#pragma unroll
            for (int mi = 0; mi < 4; mi++) acc[mi] = zf;
#pragma unroll
            for (int ks = 0; ks < 4; ks++)
#pragma unroll
                for (int mi = 0; mi < 4; mi++)
                    acc[mi] = __builtin_amdgcn_mfma_f32_16x16x32_bf16(
                        aF[mi][ks], bF[ks], acc[mi], 0, 0, 0);

            const int c0s  = cb * 256 + t * 64 + so * 16;
            const int gcol = c0s + lcol;
            const bool diagS = ((c0s & ~63) == wbase);   // => rb==cb && t==w
            const bool partS = ((c0s & ~63) == pbase);   // => cb==rb+16 && t==w
            float cs = 0.0f;                             // colsum partial
            if (diagS | partS) {
#pragma unroll
                for (int mi = 0; mi < 4; mi++)
#pragma unroll
                    for (int r = 0; r < 4; r++) {
                        int grow = wbase + mi * 16 + quad * 4 + r;
                        float s = acc[mi][r];
                        if (partS && gcol == grow + 4096) {   // rb<16 here
                            float d = s * INV_K;              // raw dot
                            pos[grow] = d;
                            pos[grow + 4096] = d;
                        }
                        float e = __builtin_amdgcn_exp2f(s);
                        if (diagS && grow == gcol) e = 0.0f;  // mask j == i
                        rs[mi * 4 + r] += e;
                        cs += e;
                    }
            } else {
#pragma unroll
                for (int mi = 0; mi < 4; mi++)
#pragma unroll
                    for (int r = 0; r < 4; r++) {
                        float e = __builtin_amdgcn_exp2f(acc[mi][r]);
                        rs[mi * 4 + r] += e;
                        cs += e;
                    }
            }
            // colsum over the wave's 64 rows: reduce across quads
            cs += __shfl_xor(cs, 16, 64);
            cs += __shfl_xor(cs, 32, 64);
            if (quad == 0) colPart[w][t * 64 + so * 16 + lcol] = cs;
        }
    }

    // row partials: reduce rs across lane bits 0-3 (16 cols per quad)
#pragma unroll
    for (int s = 1; s < 16; s <<= 1)
#pragma unroll
        for (int k = 0; k < 16; k++) rs[k] += __shfl_xor(rs[k], s, 64);

    if (lcol == 0) {
#pragma unroll
        for (int k = 0; k < 16; k++) {
            int grow = wbase + (k >> 2) * 16 + quad * 4 + (k & 3);
            rowsumP[(size_t)grow * 32 + cb] = rs[k];   // slot cb
        }
    }

    __syncthreads();   // colPart visibility for the cross-wave combine

    // col partials -> mirror rows' slot rb (skip self-tile)
    if (rb != cb) {
        float c = colPart[0][tid] + colPart[1][tid] + colPart[2][tid] + colPart[3][tid];
        rowsumP[(size_t)(cb * 256 + tid) * 32 + rb] = c;
    }
}

// ---------------------------------------------------------------------------
// Kernel 3: loss = (1/8192) * sum_i [ log(sum_c rowsumP[i][c]) - 2*pos_i ]
// ---------------------------------------------------------------------------
__global__ __launch_bounds__(128) void fin_kernel(const float* __restrict__ rowsumP,
                                                  const float* __restrict__ pos,
                                                  float* __restrict__ out) {
    int row = blockIdx.x * 128 + threadIdx.x;
    const floatx4* rp = (const floatx4*)(rowsumP + (size_t)row * 32);
    float d = 0.0f;
#pragma unroll
    for (int j = 0; j < 8; j++) {
        floatx4 q = rp[j];
        d += (q[0] + q[1]) + (q[2] + q[3]);
    }
    float v = logf(d) - pos[row] * INV_T;
#pragma unroll
    for (int s = 1; s < 64; s <<= 1) v += __shfl_xor(v, s, 64);
    __shared__ float red[2];
    if ((threadIdx.x & 63) == 0) red[threadIdx.x >> 6] = v;
    __syncthreads();
    if (threadIdx.x == 0)
        atomicAdd(out, (red[0] + red[1]) * (1.0f / 8192.0f));
}

extern "C" void kernel_launch(void* const* d_in, const int* in_sizes, int n_in,
                              void* d_out, int out_size, void* d_ws, size_t ws_size,
                              hipStream_t stream) {
    const float* p1 = (const float*)d_in[0];
    const float* p2 = (const float*)d_in[1];
    float* out = (float*)d_out;

    char* ws       = (char*)d_ws;
    uint32_t* rep2 = (uint32_t*)ws;                             // 2 MB
    float* rowsumP = (float*)(ws + (2u << 20));                 // 1 MB
    float* pos     = (float*)(ws + (3u << 20));                 // 32 KB

    nrm_kernel<<<2048, 256, 0, stream>>>(p1, p2, rep2, out);
    sim_kernel<<<dim3(32, 32), 256, 0, stream>>>((const uint4*)rep2, rowsumP, pos);
    fin_kernel<<<64, 128, 0, stream>>>(rowsumP, pos, out);
}